// Round 8
// baseline (390.712 us; speedup 1.0000x reference)
//
#include <hip/hip_runtime.h>
#include <hip/hip_bf16.h>
#include <math.h>

#define N_NODES 50000
#define N_EDGES 400000
#define N_GROUPS 3125          // N_NODES / 16 (exact)
#define E_BLOCKS 1563          // ceil(N_EDGES/256)
#define PRE_BASE (E_BLOCKS - 68)
#define SCAN_TILE 1024
#define SCAN_BLOCKS 49         // ceil(N_NODES/1024)
#define ITER_GRID 782          // ceil(3125/4) waves-per-block=4

typedef __attribute__((ext_vector_type(8))) short short8;
typedef __attribute__((ext_vector_type(4))) float f32x4;

__device__ __forceinline__ float bf16_to_f32(unsigned short v) {
  return __uint_as_float(((unsigned int)v) << 16);
}

// ---------------------------------------------------------------------------
// K0 (setup): lin0 -> out0 (ids < N), deg count (ids < E), M_B/M_A low-rank
// collapse on the last 68 blocks. (msg_C / w_node / W_lin are dead code:
// only out_edges reaches the returned log_softmax.)
// ---------------------------------------------------------------------------
__global__ __launch_bounds__(256) void setup_kernel(
    const float* __restrict__ x, const float* __restrict__ W_lin0,
    const float* __restrict__ b_lin0, const int* __restrict__ ei,
    const float* __restrict__ U_B, const float* __restrict__ V_B,
    const float* __restrict__ U_A, const float* __restrict__ V_A,
    float* __restrict__ out, int* __restrict__ degI, float* __restrict__ M_B,
    float* __restrict__ M_A) {
  __shared__ float sW0[256];
  __shared__ float sb0[16];
  int t = threadIdx.x;
  sW0[t] = W_lin0[t];
  if (t < 16) sb0[t] = b_lin0[t];
  __syncthreads();

  int gid = blockIdx.x * 256 + t;

  if (gid < N_NODES) {  // lin0
    float xr[16];
#pragma unroll
    for (int d = 0; d < 16; ++d) xr[d] = x[gid * 16 + d];
#pragma unroll
    for (int k = 0; k < 16; ++k) {
      float acc = sb0[k];
#pragma unroll
      for (int d = 0; d < 16; ++d) acc += xr[d] * sW0[d * 16 + k];
      out[gid * 16 + k] = fmaxf(acc, 0.f);
    }
  }

  if (gid < N_EDGES) atomicAdd(&degI[ei[N_EDGES + gid]], 1);

  if (blockIdx.x >= PRE_BASE) {  // M_B / M_A
    int w = (blockIdx.x - PRE_BASE) * 4 + (t >> 6);
    int lane = t & 63;
    float partial = 0.f;
    if (w < 256) {
      int i = w >> 4, j = w & 15;
#pragma unroll
      for (int r8 = 0; r8 < 8; ++r8) {
        int r = lane + 64 * r8;
        partial += U_B[i * 512 + r] * V_B[r * 16 + j];
      }
    } else if (w < 272) {
      int a = (w - 256) >> 2, b = (w - 256) & 3;
#pragma unroll
      for (int r8 = 0; r8 < 8; ++r8) {
        int r = lane + 64 * r8;
        partial += U_A[a * 512 + r] * V_A[r * 4 + b];
      }
    }
#pragma unroll
    for (int off = 32; off > 0; off >>= 1) partial += __shfl_down(partial, off);
    if (lane == 0) {
      if (w < 256) M_B[w] = partial;
      else if (w < 272) M_A[w - 256] = partial;
    }
  }
}

// ---------------------------------------------------------------------------
// K1: single-dispatch exclusive scan of degI -> row_off (+cur), decoupled
// lookback (ticket + packed sum|state). Worked verified in R5.
// ---------------------------------------------------------------------------
__global__ __launch_bounds__(256) void scan_kernel(
    const int* __restrict__ degI, int* ticket, int* st,
    int* __restrict__ row_off, int* __restrict__ cur) {
  __shared__ int sdata[256];
  __shared__ int s_tile;
  __shared__ int s_base;
  int t = threadIdx.x;
  if (t == 0) s_tile = atomicAdd(ticket, 1);
  __syncthreads();
  int tile = s_tile;
  int n0 = tile * SCAN_TILE + t * 4;

  int d0 = (n0 + 0 < N_NODES) ? degI[n0 + 0] : 0;
  int d1 = (n0 + 1 < N_NODES) ? degI[n0 + 1] : 0;
  int d2 = (n0 + 2 < N_NODES) ? degI[n0 + 2] : 0;
  int d3 = (n0 + 3 < N_NODES) ? degI[n0 + 3] : 0;
  int tsum = d0 + d1 + d2 + d3;
  sdata[t] = tsum;
  __syncthreads();
  for (int off = 1; off < 256; off <<= 1) {
    int v = (t >= off) ? sdata[t - off] : 0;
    __syncthreads();
    sdata[t] += v;
    __syncthreads();
  }
  int excl = sdata[t] - tsum;
  int agg = sdata[255];

  if (t == 0) {
    if (tile == 0) {
      atomicExch(&st[0], (agg << 2) | 2);
      s_base = 0;
    } else {
      atomicExch(&st[tile], (agg << 2) | 1);
      int run = 0, idx = tile - 1;
      while (true) {
        int w = atomicAdd(&st[idx], 0);
        int stt = w & 3;
        if (stt == 2) { run += (w >> 2); break; }
        if (stt == 1) { run += (w >> 2); --idx; }
      }
      atomicExch(&st[tile], ((run + agg) << 2) | 2);
      s_base = run;
    }
  }
  __syncthreads();

  int pre = s_base + excl;
  if (n0 + 0 < N_NODES) { row_off[n0 + 0] = pre; cur[n0 + 0] = pre; }
  pre += d0;
  if (n0 + 1 < N_NODES) { row_off[n0 + 1] = pre; cur[n0 + 1] = pre; }
  pre += d1;
  if (n0 + 2 < N_NODES) { row_off[n0 + 2] = pre; cur[n0 + 2] = pre; }
  pre += d2;
  if (n0 + 3 < N_NODES) { row_off[n0 + 3] = pre; cur[n0 + 3] = pre; }
  if (tile == SCAN_BLOCKS - 1 && t == 0) row_off[N_NODES] = N_EDGES;
}

// ---------------------------------------------------------------------------
// K2 (slot + sorted-edge materialization): per edge compute dst-sorted slot
// s, then write src_sorted[s], dst_sorted[s] and the bf16 he fragment
// (he = relu(b_e1 + ea@W_e1)) to he_sorted[s] — layout:
// he_sorted[s*16 + p*8 + tt] packs h=4tt+p (lo) / h=4tt+2+p (hi).
// ---------------------------------------------------------------------------
__global__ __launch_bounds__(256) void slot_kernel(
    const int* __restrict__ ei, const float* __restrict__ ea,
    const float* __restrict__ We1, const float* __restrict__ be1,
    int* __restrict__ cur, int* __restrict__ src_sorted,
    int* __restrict__ dst_sorted, unsigned int* __restrict__ he_sorted) {
  __shared__ float sW[128];
  __shared__ float sb[32];
  int t = threadIdx.x;
  if (t < 128) sW[t] = We1[t];
  if (t < 32) sb[t] = be1[t];
  __syncthreads();
  int e = blockIdx.x * 256 + t;
  if (e >= N_EDGES) return;
  int dst = ei[N_EDGES + e];
  int s = atomicAdd(&cur[dst], 1);
  src_sorted[s] = ei[e];
  dst_sorted[s] = dst;

  float4 v = ((const float4*)ea)[e];
  float h[32];
#pragma unroll
  for (int k = 0; k < 32; ++k) {
    float a = sb[k] + v.x * sW[k] + v.y * sW[32 + k] + v.z * sW[64 + k] +
              v.w * sW[96 + k];
    h[k] = fmaxf(a, 0.f);
  }
  unsigned int u[16];
#pragma unroll
  for (int p = 0; p < 2; ++p)
#pragma unroll
    for (int tt = 0; tt < 8; ++tt) {
      float2 pr;
      pr.x = h[4 * tt + p];
      pr.y = h[4 * tt + 2 + p];
      __hip_bfloat162 b = __float22bfloat162_rn(pr);
      u[p * 8 + tt] = *(unsigned int*)&b;
    }
  uint4* dstp = (uint4*)(he_sorted + (size_t)s * 16);
#pragma unroll
  for (int qq = 0; qq < 4; ++qq)
    dstp[qq] = make_uint4(u[4 * qq], u[4 * qq + 1], u[4 * qq + 2], u[4 * qq + 3]);
}

// ---------------------------------------------------------------------------
// K3 (fused iteration): one wave per 16-node group. The group's incoming
// edges are contiguous [row_off[n0], row_off[n0+16]) in sorted order.
// Wave: MFMA 16-edge chunks (A rows = edges, B = We2 frags in VGPRs),
// accumulate messages into a per-wave LDS agg via guarded LDS atomics,
// then GRU (4 nodes per 16-lane subgroup x 4 loops). Reads `in`, writes
// `outb` (ping-pong: no RAW hazard vs random in[src] gathers).
// Last iteration fuses the post-GRU tail + log_softmax -> res.
// ---------------------------------------------------------------------------
__global__ __launch_bounds__(256) void iter_kernel(
    const int* __restrict__ row_off, const int* __restrict__ src_sorted,
    const int* __restrict__ dst_sorted,
    const unsigned int* __restrict__ he_sorted, const float* __restrict__ We2,
    const float* __restrict__ be2, const float* __restrict__ in,
    float* __restrict__ outb, const float* __restrict__ Wroot,
    const float* __restrict__ bconv, const float* __restrict__ Wih,
    const float* __restrict__ bih, const float* __restrict__ Whh,
    const float* __restrict__ bhh, int do_final,
    const int* __restrict__ node_type, const float* __restrict__ Wlin1,
    const float* __restrict__ blin1, const float* __restrict__ Wup,
    const float* __restrict__ bup, const float* __restrict__ Wdown,
    const float* __restrict__ bdown, const float* __restrict__ M_B,
    const float* __restrict__ M_A, const float* __restrict__ wedge,
    const float* __restrict__ Wline, const float* __restrict__ bline,
    float* __restrict__ res) {
  __shared__ float sWr[256], sWihT[768], sWhhT[768], sbg[112];
  __shared__ float sAgg[4 * 256];  // per-wave [16 nodes][16 cols]

  int t = threadIdx.x;
  {
    int kk = t >> 4, dd = t & 15;
    sWr[t] = Wroot[t];
#pragma unroll
    for (int g = 0; g < 3; ++g) {
      sWihT[g * 256 + dd * 16 + kk] = Wih[g * 256 + t];
      sWhhT[g * 256 + dd * 16 + kk] = Whh[g * 256 + t];
    }
    if (t < 16) sbg[t] = bconv[t];
    else if (t < 64) sbg[t] = bih[t - 16];
    else if (t < 112) sbg[t] = bhh[t - 64];
  }

  const int wv = t >> 6;
  const int lane = t & 63;
  const int q = lane >> 4, nn = lane & 15;
  const int p = q >> 1, dbase = (q & 1) * 8;
  const int g = blockIdx.x * 4 + wv;

  // B-fragments (all of We2 + b_e2, bf16) once per wave
  short8 bfrag[17];
#pragma unroll
  for (int s = 0; s < 16; ++s) {
    int h = 2 * s + p;
    union { short8 v; __hip_bfloat162 b2[4]; } bf;
#pragma unroll
    for (int jj = 0; jj < 4; ++jj) {
      float2 w;
      w.x = We2[h * 256 + (dbase + 2 * jj) * 16 + nn];
      w.y = We2[h * 256 + (dbase + 2 * jj + 1) * 16 + nn];
      bf.b2[jj] = __float22bfloat162_rn(w);
    }
    bfrag[s] = bf.v;
  }
  {
    union { short8 v; __hip_bfloat162 b2[4]; } bf;
#pragma unroll
    for (int jj = 0; jj < 4; ++jj) {
      float2 w;
      if (q < 2) {
        w.x = be2[(dbase + 2 * jj) * 16 + nn];
        w.y = be2[(dbase + 2 * jj + 1) * 16 + nn];
      } else {
        w.x = 0.f; w.y = 0.f;
      }
      bf.b2[jj] = __float22bfloat162_rn(w);
    }
    bfrag[16] = bf.v;
  }

  int s0 = 0, s1 = 0;
  float* sa = &sAgg[wv * 256];
  if (g < N_GROUPS) {
    int n0 = g * 16;
    s0 = row_off[n0];
    s1 = row_off[n0 + 16];
    // zero this wave's agg
    sa[lane] = 0.f;
    sa[lane + 64] = 0.f;
    sa[lane + 128] = 0.f;
    sa[lane + 192] = 0.f;

    for (int j0 = s0; j0 < s1; j0 += 16) {
      int ja = j0 + nn;  // this lane's A-row edge
      bool va = (ja < s1);
      int src = va ? src_sorted[ja] : 0;
      const uint4* hp = (const uint4*)(he_sorted + (size_t)ja * 16 + p * 8);
      uint4 h0 = hp[0], h1 = hp[1];
      unsigned int heu[8] = {h0.x, h0.y, h0.z, h0.w, h1.x, h1.y, h1.z, h1.w};
      const float4* op = (const float4*)(in + src * 16 + dbase);
      float4 o0 = op[0], o1 = op[1];
      float o[8] = {o0.x, o0.y, o0.z, o0.w, o1.x, o1.y, o1.z, o1.w};

      f32x4 acc = {0.f, 0.f, 0.f, 0.f};
#pragma unroll
      for (int s = 0; s < 16; ++s) {
        unsigned int hw = heu[s >> 1];
        float he_s = __uint_as_float((s & 1) ? (hw & 0xffff0000u) : (hw << 16));
        union { short8 v; __hip_bfloat162 b2[4]; } af;
#pragma unroll
        for (int jj = 0; jj < 4; ++jj) {
          float2 pr;
          pr.x = he_s * o[2 * jj];
          pr.y = he_s * o[2 * jj + 1];
          af.b2[jj] = __float22bfloat162_rn(pr);
        }
        acc = __builtin_amdgcn_mfma_f32_16x16x32_bf16(af.v, bfrag[s], acc, 0, 0, 0);
      }
      {  // bias step
        union { short8 v; __hip_bfloat162 b2[4]; } af;
#pragma unroll
        for (int jj = 0; jj < 4; ++jj) {
          float2 pr;
          if (q < 2) { pr.x = o[2 * jj]; pr.y = o[2 * jj + 1]; }
          else { pr.x = 0.f; pr.y = 0.f; }
          af.b2[jj] = __float22bfloat162_rn(pr);
        }
        acc = __builtin_amdgcn_mfma_f32_16x16x32_bf16(af.v, bfrag[16], acc, 0, 0, 0);
      }

      // guarded accumulation: D row (q*4+r) = edge j0+q*4+r
#pragma unroll
      for (int r = 0; r < 4; ++r) {
        int j = j0 + q * 4 + r;
        if (j < s1) {
          int loc = dst_sorted[j] - g * 16;
          atomicAdd(&sa[loc * 16 + nn], acc[r]);
        }
      }
    }
  }
  __syncthreads();  // also covers the weight-staging writes at the top

  if (g >= N_GROUPS) return;

  // ---- GRU (+ fused tail): 4 nodes in parallel (16-lane subgroups), 4x ----
#pragma unroll
  for (int loop = 0; loop < 4; ++loop) {
    int nl = loop * 4 + q;
    int n = g * 16 + nl;
    int k = nn;
    float aggk = sa[nl * 16 + k];
    int r0 = row_off[n], r1 = row_off[n + 1];
    float sc = 1.f / fmaxf((float)(r1 - r0), 1.f);
    float hk = in[n * 16 + k];

    float mk = sbg[k] + aggk * sc;
#pragma unroll
    for (int d = 0; d < 16; ++d) mk += __shfl(hk, d, 16) * sWr[d * 16 + k];
    mk = fmaxf(mk, 0.f);

    float gir = sbg[16 + k], giz = sbg[32 + k], gin = sbg[48 + k];
    float ghr = sbg[64 + k], ghz = sbg[80 + k], ghn = sbg[96 + k];
#pragma unroll
    for (int d = 0; d < 16; ++d) {
      float md = __shfl(mk, d, 16);
      float hd = __shfl(hk, d, 16);
      gir += md * sWihT[d * 16 + k];
      giz += md * sWihT[256 + d * 16 + k];
      gin += md * sWihT[512 + d * 16 + k];
      ghr += hd * sWhhT[d * 16 + k];
      ghz += hd * sWhhT[256 + d * 16 + k];
      ghn += hd * sWhhT[512 + d * 16 + k];
    }
    float r = 1.f / (1.f + __expf(-(gir + ghr)));
    float z = 1.f / (1.f + __expf(-(giz + ghz)));
    float xn = gin + r * ghn;
    float ng = 1.f - 2.f / (__expf(2.f * xn) + 1.f);  // tanh, saturating
    float hnew = (1.f - z) * ng + z * hk;

    if (!do_final) {
      outb[n * 16 + k] = hnew;
      continue;
    }

    // -------- fused tail (only out_edges branch is live) --------
    float p0 = hnew * Wlin1[k * 4 + 0];
    float p1 = hnew * Wlin1[k * 4 + 1];
    float p2 = hnew * Wlin1[k * 4 + 2];
    float p3 = hnew * Wlin1[k * 4 + 3];
#pragma unroll
    for (int msk = 1; msk < 16; msk <<= 1) {
      p0 += __shfl_xor(p0, msk, 16);
      p1 += __shfl_xor(p1, msk, 16);
      p2 += __shfl_xor(p2, msk, 16);
      p3 += __shfl_xor(p3, msk, 16);
    }
    float oe0 = fmaxf(p0 + blin1[0], 0.f);
    float oe1 = fmaxf(p1 + blin1[1], 0.f);
    float oe2 = fmaxf(p2 + blin1[2], 0.f);
    float oe3 = fmaxf(p3 + blin1[3], 0.f);

    bool ev = (node_type[n] == 2);
    float ock = ev ? (bup[k] + oe0 * Wup[k] + oe1 * Wup[16 + k] +
                      oe2 * Wup[32 + k] + oe3 * Wup[48 + k])
                   : hnew;

    float msgBk = 0.f;
#pragma unroll
    for (int d = 0; d < 16; ++d) msgBk += __shfl(ock, d, 16) * M_B[d * 16 + k];
    msgBk = fmaxf(msgBk, 0.f);

    float q0 = msgBk * Wdown[k * 4 + 0];
    float q1 = msgBk * Wdown[k * 4 + 1];
    float q2 = msgBk * Wdown[k * 4 + 2];
    float q3 = msgBk * Wdown[k * 4 + 3];
#pragma unroll
    for (int msk = 1; msk < 16; msk <<= 1) {
      q0 += __shfl_xor(q0, msk, 16);
      q1 += __shfl_xor(q1, msk, 16);
      q2 += __shfl_xor(q2, msk, 16);
      q3 += __shfl_xor(q3, msk, 16);
    }
    float mtb0 = q0 + bdown[0], mtb1 = q1 + bdown[1];
    float mtb2 = q2 + bdown[2], mtb3 = q3 + bdown[3];

    float mta0 = fmaxf(oe0 * M_A[0] + oe1 * M_A[4] + oe2 * M_A[8] + oe3 * M_A[12], 0.f);
    float mta1 = fmaxf(oe0 * M_A[1] + oe1 * M_A[5] + oe2 * M_A[9] + oe3 * M_A[13], 0.f);
    float mta2 = fmaxf(oe0 * M_A[2] + oe1 * M_A[6] + oe2 * M_A[10] + oe3 * M_A[14], 0.f);
    float mta3 = fmaxf(oe0 * M_A[3] + oe1 * M_A[7] + oe2 * M_A[11] + oe3 * M_A[15], 0.f);

    float c0 = wedge[0] * (mta0 * mtb0);
    float c1 = wedge[1] * (mta1 * mtb1);
    float c2 = wedge[2] * (mta2 * mtb2);
    float c3 = wedge[3] * (mta3 * mtb3);

    float f0 = oe0 + fmaxf(bline[0] + c0 * Wline[0] + c1 * Wline[4] + c2 * Wline[8] + c3 * Wline[12], 0.f);
    float f1 = oe1 + fmaxf(bline[1] + c0 * Wline[1] + c1 * Wline[5] + c2 * Wline[9] + c3 * Wline[13], 0.f);
    float f2 = oe2 + fmaxf(bline[2] + c0 * Wline[2] + c1 * Wline[6] + c2 * Wline[10] + c3 * Wline[14], 0.f);
    float f3 = oe3 + fmaxf(bline[3] + c0 * Wline[3] + c1 * Wline[7] + c2 * Wline[11] + c3 * Wline[15], 0.f);

    float mx = fmaxf(fmaxf(f0, f1), fmaxf(f2, f3));
    float se = __expf(f0 - mx) + __expf(f1 - mx) + __expf(f2 - mx) +
               __expf(f3 - mx);
    float lse = mx + __logf(se);
    if (k < 4) {
      float v = (k == 0) ? f0 : (k == 1) ? f1 : (k == 2) ? f2 : f3;
      res[n * 4 + k] = v - lse;
    }
  }
}

// ---------------------------------------------------------------------------
extern "C" void kernel_launch(void* const* d_in, const int* in_sizes, int n_in,
                              void* d_out, int out_size, void* d_ws,
                              size_t ws_size, hipStream_t stream) {
  const float* x       = (const float*)d_in[0];
  const int* node_type = (const int*)d_in[1];
  const int* ei        = (const int*)d_in[2];
  const float* ea      = (const float*)d_in[3];
  const float* W_lin0  = (const float*)d_in[4];
  const float* b_lin0  = (const float*)d_in[5];
  const float* W_root  = (const float*)d_in[6];
  const float* b_conv  = (const float*)d_in[7];
  const float* W_e1    = (const float*)d_in[8];
  const float* b_e1    = (const float*)d_in[9];
  const float* W_e2    = (const float*)d_in[10];
  const float* b_e2    = (const float*)d_in[11];
  const float* W_ih    = (const float*)d_in[12];
  const float* b_ih    = (const float*)d_in[13];
  const float* W_hh    = (const float*)d_in[14];
  const float* b_hh    = (const float*)d_in[15];
  const float* W_lin1  = (const float*)d_in[16];
  const float* b_lin1  = (const float*)d_in[17];
  const float* W_up    = (const float*)d_in[18];
  const float* b_up    = (const float*)d_in[19];
  const float* W_down  = (const float*)d_in[20];
  const float* b_down  = (const float*)d_in[21];
  const float* U_B     = (const float*)d_in[22];
  const float* V_B     = (const float*)d_in[23];
  // d_in[24..25] U_C,V_C and d_in[28..30] w_node,W_lin,b_lin : dead code
  const float* U_A     = (const float*)d_in[26];
  const float* V_A     = (const float*)d_in[27];
  const float* w_edge  = (const float*)d_in[31];
  const float* W_line  = (const float*)d_in[32];
  const float* b_line  = (const float*)d_in[33];

  float* ws = (float*)d_ws;
  float* out0 = ws;                                   // N*16 f32
  float* out1 = out0 + N_NODES * 16;                  // N*16 f32
  unsigned int* he_sorted = (unsigned int*)(out1 + N_NODES * 16);  // (E+16)*16
  int* src_sorted = (int*)(he_sorted + (size_t)(N_EDGES + 16) * 16);  // E+16
  int* dst_sorted = src_sorted + N_EDGES + 16;        // E+16
  float* M_B = (float*)(dst_sorted + N_EDGES + 16);   // 256
  float* M_A = M_B + 256;                             // 16
  int* degI = (int*)(M_A + 16);                       // N
  int* ticket = degI + N_NODES;                       // 1
  int* st = ticket + 1;                               // 63 (pad)
  int* row_off = st + 63;                             // N+1
  int* cur = row_off + N_NODES + 1;                   // N

  // zero degI + ticket + st in one memset
  hipMemsetAsync(degI, 0, (N_NODES + 64) * sizeof(int), stream);

  setup_kernel<<<E_BLOCKS, 256, 0, stream>>>(x, W_lin0, b_lin0, ei, U_B, V_B,
                                             U_A, V_A, out0, degI, M_B, M_A);
  scan_kernel<<<SCAN_BLOCKS, 256, 0, stream>>>(degI, ticket, st, row_off, cur);
  slot_kernel<<<E_BLOCKS, 256, 0, stream>>>(ei, ea, W_e1, b_e1, cur, src_sorted,
                                            dst_sorted, he_sorted);

  float* bufs[2] = {out0, out1};
  for (int it = 0; it < 3; ++it) {
    iter_kernel<<<ITER_GRID, 256, 0, stream>>>(
        row_off, src_sorted, dst_sorted, he_sorted, W_e2, b_e2, bufs[it & 1],
        bufs[(it & 1) ^ 1], W_root, b_conv, W_ih, b_ih, W_hh, b_hh,
        (it == 2) ? 1 : 0, node_type, W_lin1, b_lin1, W_up, b_up, W_down,
        b_down, M_B, M_A, w_edge, W_line, b_line, (float*)d_out);
  }
}